// Round 4
// baseline (10504.004 us; speedup 1.0000x reference)
//
#include <hip/hip_runtime.h>

#define TT 512
#define BB 64
#define HH 1024
#define EE 512
#define VV 50000
#define BBHH (BB*HH)
#define NBLK 128

typedef __attribute__((ext_vector_type(8))) short bf16x8;
typedef __attribute__((ext_vector_type(4))) float f32x4;

__device__ inline float b2f(unsigned short b){
  unsigned int u = ((unsigned int)b) << 16;
  float f; __builtin_memcpy(&f, &u, 4); return f;
}
__device__ inline unsigned short f2b(float f){
  unsigned int u; __builtin_memcpy(&u, &f, 4);
  unsigned int r = (u + 0x7FFFu + ((u >> 16) & 1u)) >> 16;
  return (unsigned short)r;
}
__device__ inline float sigmoidf_(float x){ return 1.0f / (1.0f + __expf(-x)); }
__device__ inline float tanhf_(float x){ float e = __expf(2.0f * x); return 1.0f - 2.0f / (e + 1.0f); }

__device__ inline bf16x8 pack8(float4 a, float4 b){
  bf16x8 r;
  r[0] = (short)f2b(a.x); r[1] = (short)f2b(a.y); r[2] = (short)f2b(a.z); r[3] = (short)f2b(a.w);
  r[4] = (short)f2b(b.x); r[5] = (short)f2b(b.y); r[6] = (short)f2b(b.z); r[7] = (short)f2b(b.w);
  return r;
}

// ---------------- cast fp32 -> bf16 ----------------
__global__ void cast_f2b(const float* __restrict__ src, unsigned short* __restrict__ dst, long n){
  long i = ((long)blockIdx.x * blockDim.x + threadIdx.x) * 4;
  long stride = (long)gridDim.x * blockDim.x * 4;
  for (; i + 3 < n; i += stride){
    float4 v = *reinterpret_cast<const float4*>(src + i);
    ushort4 r;
    r.x = f2b(v.x); r.y = f2b(v.y); r.z = f2b(v.z); r.w = f2b(v.w);
    *reinterpret_cast<ushort4*>(dst + i) = r;
  }
}

// ---------------- init: h0 fp32 [2,B,H] -> per-layer bf16 init rows ----------------
__global__ void init_h(const float* __restrict__ h0,
                       unsigned short* __restrict__ h0i, unsigned short* __restrict__ h1i){
  int i = blockIdx.x * blockDim.x + threadIdx.x;   // 0..BBHH-1
  h0i[i] = f2b(h0[i]);
  h1i[i] = f2b(h0[BBHH + i]);
}

// ---------------- wait / arrive (relaxed agent atomics only; 4 lines x 32) ----------------
__device__ __forceinline__ void wait128(unsigned* c){
  if (threadIdx.x == 0){
    for (;;){
      unsigned s = __hip_atomic_load(c +  0, __ATOMIC_RELAXED, __HIP_MEMORY_SCOPE_AGENT)
                 + __hip_atomic_load(c + 32, __ATOMIC_RELAXED, __HIP_MEMORY_SCOPE_AGENT)
                 + __hip_atomic_load(c + 64, __ATOMIC_RELAXED, __HIP_MEMORY_SCOPE_AGENT)
                 + __hip_atomic_load(c + 96, __ATOMIC_RELAXED, __HIP_MEMORY_SCOPE_AGENT);
      if (s >= (unsigned)NBLK) break;
      __builtin_amdgcn_s_sleep(4);
    }
  }
  __syncthreads();
}

__device__ __forceinline__ void arrive(unsigned* c, int sub){
  asm volatile("s_waitcnt vmcnt(0)" ::: "memory");
  __syncthreads();
  if (threadIdx.x == 0)
    __hip_atomic_fetch_add(c + sub * 32, 1u, __ATOMIC_RELAXED, __HIP_MEMORY_SCOPE_AGENT);
}

// ---------------- fused 2-layer persistent LSTM ----------------
// 128 blocks x 256 threads; block owns 8 hidden units of BOTH layers.
// Interval iv: L0 computes t=iv (if iv<TT), L1 computes t=iv-1 (if iv>=1).
// One wait (ctr[iv-1]) and one arrive (ctr[iv]) per interval.
// h0[iv-1] rows feed BOTH L0's recurrent part and L1's x part (loaded once).
// Lane mapping (per m in 0..1): A-row l16 -> (g=l16&3, u=2*(l16>>2)+m);
// D row hi*4+i -> unit j0+2*hi+m, gate i; lane owns batch bown=wid*16+l16.
__global__ __launch_bounds__(256, 1) void lstm_fused(
    const int* __restrict__ inputs, const float* __restrict__ c0,
    const unsigned short* __restrict__ emb_bf,
    const float* __restrict__ Wih0, const float* __restrict__ Whh0,
    const float* __restrict__ Wih1, const float* __restrict__ Whh1,
    const unsigned short* __restrict__ h0i, const unsigned short* __restrict__ h1i,
    unsigned short* __restrict__ hist0, unsigned short* __restrict__ hist1,
    const float* __restrict__ decW, const float* __restrict__ decb,
    float* __restrict__ dec_out, float* __restrict__ hn, float* __restrict__ cn,
    unsigned* __restrict__ ctr)
{
  // [L][m] regions of 16 slots x 64 lanes x f32x4 (dense 16B/lane stride)
  __shared__ float lds[2 * 2 * 16 * 64 * 4];   // 64 KB
  #define LIDX(L, m, s) ((((L) * 2 + (m)) * 16 + (s)) * 64 + lane) * 4

  const int tid  = threadIdx.x;
  const int lane = tid & 63;
  const int wid  = tid >> 6;
  const int l16  = lane & 15;
  const int hi   = lane >> 4;
  const int kq   = hi << 3;
  const int j0   = blockIdx.x * 8;
  const int sub  = blockIdx.x & 3;
  const int bown = wid * 16 + l16;

  // ---- weight preload into registers (fp32 -> bf16 in-register) ----
  bf16x8 wx0[2][4], wh0[2][8], wx1[2][8], wh1[2][8];
  #pragma unroll
  for (int m = 0; m < 2; ++m){
    const int g = l16 & 3;
    const int u = 2 * (l16 >> 2) + m;
    const float* r0x = Wih0 + (size_t)(g * HH + j0 + u) * EE;
    const float* r0h = Whh0 + (size_t)(g * HH + j0 + u) * HH;
    const float* r1x = Wih1 + (size_t)(g * HH + j0 + u) * HH;
    const float* r1h = Whh1 + (size_t)(g * HH + j0 + u) * HH;
    #pragma unroll
    for (int kk = 0; kk < 4; ++kk){
      int k0 = wid * 128 + kk * 32 + kq;
      wx0[m][kk] = pack8(*reinterpret_cast<const float4*>(r0x + k0),
                         *reinterpret_cast<const float4*>(r0x + k0 + 4));
    }
    #pragma unroll
    for (int kk = 0; kk < 8; ++kk){
      int k0 = wid * 256 + kk * 32 + kq;
      wh0[m][kk] = pack8(*reinterpret_cast<const float4*>(r0h + k0),
                         *reinterpret_cast<const float4*>(r0h + k0 + 4));
      wx1[m][kk] = pack8(*reinterpret_cast<const float4*>(r1x + k0),
                         *reinterpret_cast<const float4*>(r1x + k0 + 4));
      wh1[m][kk] = pack8(*reinterpret_cast<const float4*>(r1h + k0),
                         *reinterpret_cast<const float4*>(r1h + k0 + 4));
    }
  }

  // ---- per-lane cell state: units j0+2*hi+m, batch bown ----
  float cs0[2], cs1[2];
  #pragma unroll
  for (int m = 0; m < 2; ++m){
    cs0[m] = c0[(size_t)bown * HH + j0 + 2 * hi + m];
    cs1[m] = c0[(size_t)BBHH + (size_t)bown * HH + j0 + 2 * hi + m];
  }
  float pooldec = 0.0f;
  const float dwv0 = decW[j0 + 2 * hi], dwv1 = decW[j0 + 2 * hi + 1];

  for (int iv = 0; iv <= TT; ++iv){
    const bool a0 = iv < TT;
    const bool a1 = iv >= 1;

    f32x4 acc0[2][4], acc1[2][4];
    #pragma unroll
    for (int m = 0; m < 2; ++m)
      #pragma unroll
      for (int nt = 0; nt < 4; ++nt){
        acc0[m][nt] = (f32x4){0.f,0.f,0.f,0.f};
        acc1[m][nt] = (f32x4){0.f,0.f,0.f,0.f};
      }

    // ---------- L0 x-part (emb) BEFORE the wait ----------
    if (a0){
      const unsigned short* xr[4];
      #pragma unroll
      for (int nt = 0; nt < 4; ++nt)
        xr[nt] = emb_bf + (size_t)inputs[iv * BB + nt * 16 + l16] * EE;
      #pragma unroll
      for (int kk = 0; kk < 4; ++kk){
        const int kb = wid * 128 + kk * 32 + kq;
        #pragma unroll
        for (int nt = 0; nt < 4; ++nt){
          bf16x8 bf = *reinterpret_cast<const bf16x8*>(xr[nt] + kb);
          acc0[0][nt] = __builtin_amdgcn_mfma_f32_16x16x32_bf16(wx0[0][kk], bf, acc0[0][nt], 0, 0, 0);
          acc0[1][nt] = __builtin_amdgcn_mfma_f32_16x16x32_bf16(wx0[1][kk], bf, acc0[1][nt], 0, 0, 0);
        }
      }
    }

    if (iv >= 1) wait128(ctr + (size_t)(iv - 1) * 128);

    // ---------- shared h0[iv-1] rows: L0 recurrent + L1 x ----------
    {
      const unsigned short* hs = (iv == 0) ? h0i : hist0 + (size_t)(iv - 1) * BBHH;
      const unsigned short* hr[4];
      #pragma unroll
      for (int nt = 0; nt < 4; ++nt)
        hr[nt] = hs + (size_t)(nt * 16 + l16) * HH;

      if (a0 && a1){
        #pragma unroll
        for (int kk = 0; kk < 8; ++kk){
          const int kb = wid * 256 + kk * 32 + kq;
          #pragma unroll
          for (int nt = 0; nt < 4; ++nt){
            bf16x8 bf = *reinterpret_cast<const bf16x8*>(hr[nt] + kb);
            acc0[0][nt] = __builtin_amdgcn_mfma_f32_16x16x32_bf16(wh0[0][kk], bf, acc0[0][nt], 0, 0, 0);
            acc0[1][nt] = __builtin_amdgcn_mfma_f32_16x16x32_bf16(wh0[1][kk], bf, acc0[1][nt], 0, 0, 0);
            acc1[0][nt] = __builtin_amdgcn_mfma_f32_16x16x32_bf16(wx1[0][kk], bf, acc1[0][nt], 0, 0, 0);
            acc1[1][nt] = __builtin_amdgcn_mfma_f32_16x16x32_bf16(wx1[1][kk], bf, acc1[1][nt], 0, 0, 0);
          }
        }
      } else if (a0){            // iv == 0
        #pragma unroll
        for (int kk = 0; kk < 8; ++kk){
          const int kb = wid * 256 + kk * 32 + kq;
          #pragma unroll
          for (int nt = 0; nt < 4; ++nt){
            bf16x8 bf = *reinterpret_cast<const bf16x8*>(hr[nt] + kb);
            acc0[0][nt] = __builtin_amdgcn_mfma_f32_16x16x32_bf16(wh0[0][kk], bf, acc0[0][nt], 0, 0, 0);
            acc0[1][nt] = __builtin_amdgcn_mfma_f32_16x16x32_bf16(wh0[1][kk], bf, acc0[1][nt], 0, 0, 0);
          }
        }
      } else {                   // iv == TT
        #pragma unroll
        for (int kk = 0; kk < 8; ++kk){
          const int kb = wid * 256 + kk * 32 + kq;
          #pragma unroll
          for (int nt = 0; nt < 4; ++nt){
            bf16x8 bf = *reinterpret_cast<const bf16x8*>(hr[nt] + kb);
            acc1[0][nt] = __builtin_amdgcn_mfma_f32_16x16x32_bf16(wx1[0][kk], bf, acc1[0][nt], 0, 0, 0);
            acc1[1][nt] = __builtin_amdgcn_mfma_f32_16x16x32_bf16(wx1[1][kk], bf, acc1[1][nt], 0, 0, 0);
          }
        }
      }
    }

    // ---------- L1 recurrent part: h1[iv-2] ----------
    if (a1){
      const unsigned short* hs = (iv == 1) ? h1i : hist1 + (size_t)(iv - 2) * BBHH;
      const unsigned short* hr[4];
      #pragma unroll
      for (int nt = 0; nt < 4; ++nt)
        hr[nt] = hs + (size_t)(nt * 16 + l16) * HH;
      #pragma unroll
      for (int kk = 0; kk < 8; ++kk){
        const int kb = wid * 256 + kk * 32 + kq;
        #pragma unroll
        for (int nt = 0; nt < 4; ++nt){
          bf16x8 bf = *reinterpret_cast<const bf16x8*>(hr[nt] + kb);
          acc1[0][nt] = __builtin_amdgcn_mfma_f32_16x16x32_bf16(wh1[0][kk], bf, acc1[0][nt], 0, 0, 0);
          acc1[1][nt] = __builtin_amdgcn_mfma_f32_16x16x32_bf16(wh1[1][kk], bf, acc1[1][nt], 0, 0, 0);
        }
      }
    }

    // ---------- cross-wave K reduction (dense 16B/lane stride) ----------
    #pragma unroll
    for (int m = 0; m < 2; ++m)
      #pragma unroll
      for (int nt = 0; nt < 4; ++nt){
        *reinterpret_cast<f32x4*>(&lds[LIDX(0, m, wid * 4 + nt)]) = acc0[m][nt];
        *reinterpret_cast<f32x4*>(&lds[LIDX(1, m, wid * 4 + nt)]) = acc1[m][nt];
      }
    __syncthreads();
    f32x4 s0[2], s1[2];
    #pragma unroll
    for (int m = 0; m < 2; ++m){
      s0[m] = (f32x4){0.f,0.f,0.f,0.f};
      s1[m] = (f32x4){0.f,0.f,0.f,0.f};
      #pragma unroll
      for (int w = 0; w < 4; ++w){
        s0[m] += *reinterpret_cast<f32x4*>(&lds[LIDX(0, m, w * 4 + wid)]);
        s1[m] += *reinterpret_cast<f32x4*>(&lds[LIDX(1, m, w * 4 + wid)]);
      }
    }

    // ---------- cell updates + publish ----------
    if (a0){
      float hv[2];
      #pragma unroll
      for (int m = 0; m < 2; ++m){
        float gi = sigmoidf_(s0[m][0]), gf = sigmoidf_(s0[m][1]);
        float gg = tanhf_(s0[m][2]),    go = sigmoidf_(s0[m][3]);
        cs0[m] = gf * cs0[m] + gi * gg;
        hv[m] = go * tanhf_(cs0[m]);
      }
      unsigned w = (unsigned)f2b(hv[0]) | ((unsigned)f2b(hv[1]) << 16);
      __hip_atomic_store(reinterpret_cast<unsigned*>(hist0 + (size_t)iv * BBHH + (size_t)bown * HH + j0 + 2 * hi),
                         w, __ATOMIC_RELAXED, __HIP_MEMORY_SCOPE_AGENT);
      if (iv == TT - 1){
        size_t o = (size_t)bown * HH + j0 + 2 * hi;
        *reinterpret_cast<float2*>(hn + o) = make_float2(hv[0], hv[1]);
        *reinterpret_cast<float2*>(cn + o) = make_float2(cs0[0], cs0[1]);
      }
    }
    if (a1){
      const int t1 = iv - 1;
      float hv[2];
      #pragma unroll
      for (int m = 0; m < 2; ++m){
        float gi = sigmoidf_(s1[m][0]), gf = sigmoidf_(s1[m][1]);
        float gg = tanhf_(s1[m][2]),    go = sigmoidf_(s1[m][3]);
        cs1[m] = gf * cs1[m] + gi * gg;
        hv[m] = go * tanhf_(cs1[m]);
      }
      unsigned w = (unsigned)f2b(hv[0]) | ((unsigned)f2b(hv[1]) << 16);
      __hip_atomic_store(reinterpret_cast<unsigned*>(hist1 + (size_t)t1 * BBHH + (size_t)bown * HH + j0 + 2 * hi),
                         w, __ATOMIC_RELAXED, __HIP_MEMORY_SCOPE_AGENT);
      pooldec += hv[0] * dwv0 + hv[1] * dwv1;
      if (t1 == TT - 1){
        size_t o = (size_t)BBHH + (size_t)bown * HH + j0 + 2 * hi;
        *reinterpret_cast<float2*>(hn + o) = make_float2(hv[0], hv[1]);
        *reinterpret_cast<float2*>(cn + o) = make_float2(cs1[0], cs1[1]);
      }
    }

    if (iv < TT) arrive(ctr + (size_t)iv * 128, sub);
  }

  // ---------- decode ----------
  pooldec += __shfl_xor(pooldec, 16);
  pooldec += __shfl_xor(pooldec, 32);
  if (hi == 0){
    float contrib = pooldec * (1.0f / (float)TT);
    if (blockIdx.x == 0) contrib += decb[0];
    atomicAdd(&dec_out[bown], contrib);
  }
  #undef LIDX
}

extern "C" void kernel_launch(void* const* d_in, const int* in_sizes, int n_in,
                              void* d_out, int out_size, void* d_ws, size_t ws_size,
                              hipStream_t stream){
  const int*   inputs = (const int*)d_in[0];
  const float* h0     = (const float*)d_in[1];
  const float* c0     = (const float*)d_in[2];
  const float* emb    = (const float*)d_in[3];
  const float* Wih0   = (const float*)d_in[4];
  const float* Whh0   = (const float*)d_in[5];
  const float* Wih1   = (const float*)d_in[6];
  const float* Whh1   = (const float*)d_in[7];
  const float* decW   = (const float*)d_in[8];
  const float* decb   = (const float*)d_in[9];

  char* ws = (char*)d_ws;
  size_t off = 0;
  auto alloc = [&](size_t bytes) -> void* {
    void* p = ws + off;
    off += (bytes + 255) & ~(size_t)255;
    return p;
  };
  unsigned short* emb_bf = (unsigned short*)alloc((size_t)VV * EE * 2);      // 51.2 MB
  unsigned short* hist0  = (unsigned short*)alloc((size_t)TT * BBHH * 2);    // 64 MB
  unsigned short* hist1  = (unsigned short*)alloc((size_t)TT * BBHH * 2);    // 64 MB
  unsigned short* h0i    = (unsigned short*)alloc((size_t)BBHH * 2);
  unsigned short* h1i    = (unsigned short*)alloc((size_t)BBHH * 2);
  unsigned int*   ctr    = (unsigned int*)alloc((size_t)TT * 128 * 4);       // 256 KB

  float* out = (float*)d_out;            // decoded [B]
  float* hn  = out + BB;                 // [2,B,H]
  float* cn  = out + BB + 2 * BBHH;      // [2,B,H]

  hipMemsetAsync(ctr, 0, (size_t)TT * 128 * 4, stream);
  hipMemsetAsync(out, 0, BB * 4, stream);

  cast_f2b<<<2048, 256, 0, stream>>>(emb, emb_bf, (long)VV * EE);
  init_h<<<BBHH / 256, 256, 0, stream>>>(h0, h0i, h1i);

  lstm_fused<<<NBLK, 256, 0, stream>>>(inputs, c0, emb_bf,
                                       Wih0, Whh0, Wih1, Whh1,
                                       h0i, h1i, hist0, hist1,
                                       decW, decb, out, hn, cn, ctr);
}

// Round 5
// 7844.212 us; speedup vs baseline: 1.3391x; 1.3391x over previous
//
#include <hip/hip_runtime.h>

#define TT 512
#define BB 64
#define HH 1024
#define EE 512
#define VV 50000
#define BBHH (BB*HH)
#define BPL 128
#define NBLK 256

typedef __attribute__((ext_vector_type(8))) short bf16x8;
typedef __attribute__((ext_vector_type(4))) float f32x4;

__device__ inline unsigned short f2b(float f){
  unsigned int u; __builtin_memcpy(&u, &f, 4);
  unsigned int r = (u + 0x7FFFu + ((u >> 16) & 1u)) >> 16;
  return (unsigned short)r;
}
__device__ inline float sigmoidf_(float x){ return 1.0f / (1.0f + __expf(-x)); }
__device__ inline float tanhf_(float x){ float e = __expf(2.0f * x); return 1.0f - 2.0f / (e + 1.0f); }

__device__ inline bf16x8 pack8(float4 a, float4 b){
  bf16x8 r;
  r[0] = (short)f2b(a.x); r[1] = (short)f2b(a.y); r[2] = (short)f2b(a.z); r[3] = (short)f2b(a.w);
  r[4] = (short)f2b(b.x); r[5] = (short)f2b(b.y); r[6] = (short)f2b(b.z); r[7] = (short)f2b(b.w);
  return r;
}

// ---------------- cast fp32 -> bf16 ----------------
__global__ void cast_f2b(const float* __restrict__ src, unsigned short* __restrict__ dst, long n){
  long i = ((long)blockIdx.x * blockDim.x + threadIdx.x) * 4;
  long stride = (long)gridDim.x * blockDim.x * 4;
  for (; i + 3 < n; i += stride){
    float4 v = *reinterpret_cast<const float4*>(src + i);
    ushort4 r;
    r.x = f2b(v.x); r.y = f2b(v.y); r.z = f2b(v.z); r.w = f2b(v.w);
    *reinterpret_cast<ushort4*>(dst + i) = r;
  }
}

// ---------------- init: h0 fp32 [2,B,H] -> per-layer bf16 init rows ----------------
__global__ void init_h(const float* __restrict__ h0,
                       unsigned short* __restrict__ h0i, unsigned short* __restrict__ h1i){
  int i = blockIdx.x * blockDim.x + threadIdx.x;   // 0..BBHH-1
  h0i[i] = f2b(h0[i]);
  h1i[i] = f2b(h0[BBHH + i]);
}

// ---------------- epoch-flag wait: every wave polls all 128 flags itself ----------------
// flags[bid] = last completed step + 1, stored with a plain relaxed agent store
// (no RMW -> no MALL serialization). 2 sc1 loads/lane, __all over the wave.
__device__ __forceinline__ void wait_layer(const unsigned* __restrict__ f, unsigned e, int lane){
  for (;;){
    unsigned a = __hip_atomic_load(f + lane,      __ATOMIC_RELAXED, __HIP_MEMORY_SCOPE_AGENT);
    unsigned b = __hip_atomic_load(f + 64 + lane, __ATOMIC_RELAXED, __HIP_MEMORY_SCOPE_AGENT);
    if (__all(a >= e && b >= e)) break;
  }
}

// publish: drain this wave's sc1 stores, block-barrier, one flag store
__device__ __forceinline__ void publish(unsigned* __restrict__ f, int bid_l, unsigned e){
  asm volatile("s_waitcnt vmcnt(0)" ::: "memory");
  __syncthreads();
  if (threadIdx.x == 0)
    __hip_atomic_store(f + bid_l, e, __ATOMIC_RELAXED, __HIP_MEMORY_SCOPE_AGENT);
}

// Lane mapping (per m in 0..1): A-row l16 -> (g=l16&3, u=2*(l16>>2)+m);
// D row hi*4+i -> unit j0+2*hi+m, gate i; lane owns batch bown=wid*16+l16.
#define LIDX(m, s) ((((m) * 16 + (s)) * 64 + lane) * 4)

__device__ void run_l0(
    int bid_l, int lane, int wid, int l16, int hi, int kq,
    const int* __restrict__ inputs, const float* __restrict__ c0,
    const unsigned short* __restrict__ emb_bf,
    const float* __restrict__ Wih0, const float* __restrict__ Whh0,
    const unsigned short* __restrict__ h0i,
    unsigned short* __restrict__ hist0,
    float* __restrict__ hn, float* __restrict__ cn,
    unsigned* __restrict__ flags0, float* lds)
{
  const int j0 = bid_l * 8;
  const int bown = wid * 16 + l16;

  bf16x8 wx[2][4], wh[2][8];
  #pragma unroll
  for (int m = 0; m < 2; ++m){
    const int g = l16 & 3;
    const int u = 2 * (l16 >> 2) + m;
    const float* rx = Wih0 + (size_t)(g * HH + j0 + u) * EE;
    const float* rh = Whh0 + (size_t)(g * HH + j0 + u) * HH;
    #pragma unroll
    for (int kk = 0; kk < 4; ++kk){
      int k0 = wid * 128 + kk * 32 + kq;
      wx[m][kk] = pack8(*reinterpret_cast<const float4*>(rx + k0),
                        *reinterpret_cast<const float4*>(rx + k0 + 4));
    }
    #pragma unroll
    for (int kk = 0; kk < 8; ++kk){
      int k0 = wid * 256 + kk * 32 + kq;
      wh[m][kk] = pack8(*reinterpret_cast<const float4*>(rh + k0),
                        *reinterpret_cast<const float4*>(rh + k0 + 4));
    }
  }

  float cs[2];
  #pragma unroll
  for (int m = 0; m < 2; ++m)
    cs[m] = c0[(size_t)bown * HH + j0 + 2 * hi + m];

  for (int t = 0; t < TT; ++t){
    f32x4 acc[2][4];
    #pragma unroll
    for (int m = 0; m < 2; ++m)
      #pragma unroll
      for (int nt = 0; nt < 4; ++nt)
        acc[m][nt] = (f32x4){0.f,0.f,0.f,0.f};

    // x-part (emb) before the wait — dependency-free
    {
      const unsigned short* xr[4];
      #pragma unroll
      for (int nt = 0; nt < 4; ++nt)
        xr[nt] = emb_bf + (size_t)inputs[t * BB + nt * 16 + l16] * EE;
      #pragma unroll
      for (int kk = 0; kk < 4; ++kk){
        const int kb = wid * 128 + kk * 32 + kq;
        #pragma unroll
        for (int nt = 0; nt < 4; ++nt){
          bf16x8 bf = *reinterpret_cast<const bf16x8*>(xr[nt] + kb);
          acc[0][nt] = __builtin_amdgcn_mfma_f32_16x16x32_bf16(wx[0][kk], bf, acc[0][nt], 0, 0, 0);
          acc[1][nt] = __builtin_amdgcn_mfma_f32_16x16x32_bf16(wx[1][kk], bf, acc[1][nt], 0, 0, 0);
        }
      }
    }

    if (t > 0) wait_layer(flags0, (unsigned)t, lane);

    // recurrent part
    {
      const unsigned short* hs = (t == 0) ? h0i : hist0 + (size_t)(t - 1) * BBHH;
      const unsigned short* hr[4];
      #pragma unroll
      for (int nt = 0; nt < 4; ++nt)
        hr[nt] = hs + (size_t)(nt * 16 + l16) * HH;
      #pragma unroll
      for (int kk = 0; kk < 8; ++kk){
        const int kb = wid * 256 + kk * 32 + kq;
        #pragma unroll
        for (int nt = 0; nt < 4; ++nt){
          bf16x8 bf = *reinterpret_cast<const bf16x8*>(hr[nt] + kb);
          acc[0][nt] = __builtin_amdgcn_mfma_f32_16x16x32_bf16(wh[0][kk], bf, acc[0][nt], 0, 0, 0);
          acc[1][nt] = __builtin_amdgcn_mfma_f32_16x16x32_bf16(wh[1][kk], bf, acc[1][nt], 0, 0, 0);
        }
      }
    }

    // cross-wave K reduction (dense 16B/lane -> 0 bank conflicts)
    #pragma unroll
    for (int m = 0; m < 2; ++m)
      #pragma unroll
      for (int nt = 0; nt < 4; ++nt)
        *reinterpret_cast<f32x4*>(&lds[LIDX(m, wid * 4 + nt)]) = acc[m][nt];
    __syncthreads();
    f32x4 s[2];
    #pragma unroll
    for (int m = 0; m < 2; ++m){
      s[m] = (f32x4){0.f,0.f,0.f,0.f};
      #pragma unroll
      for (int w = 0; w < 4; ++w)
        s[m] += *reinterpret_cast<f32x4*>(&lds[LIDX(m, w * 4 + wid)]);
    }

    float hv[2];
    #pragma unroll
    for (int m = 0; m < 2; ++m){
      float gi = sigmoidf_(s[m][0]), gf = sigmoidf_(s[m][1]);
      float gg = tanhf_(s[m][2]),    go = sigmoidf_(s[m][3]);
      cs[m] = gf * cs[m] + gi * gg;
      hv[m] = go * tanhf_(cs[m]);
    }
    unsigned w = (unsigned)f2b(hv[0]) | ((unsigned)f2b(hv[1]) << 16);
    __hip_atomic_store(reinterpret_cast<unsigned*>(hist0 + (size_t)t * BBHH + (size_t)bown * HH + j0 + 2 * hi),
                       w, __ATOMIC_RELAXED, __HIP_MEMORY_SCOPE_AGENT);
    if (t == TT - 1){
      size_t o = (size_t)bown * HH + j0 + 2 * hi;
      *reinterpret_cast<float2*>(hn + o) = make_float2(hv[0], hv[1]);
      *reinterpret_cast<float2*>(cn + o) = make_float2(cs[0], cs[1]);
    }

    publish(flags0, bid_l, (unsigned)(t + 1));
  }
}

__device__ void run_l1(
    int bid_l, int lane, int wid, int l16, int hi, int kq,
    const float* __restrict__ c0,
    const float* __restrict__ Wih1, const float* __restrict__ Whh1,
    const unsigned short* __restrict__ h1i,
    const unsigned short* __restrict__ hist0, unsigned short* __restrict__ hist1,
    const float* __restrict__ decW, const float* __restrict__ decb,
    float* __restrict__ dec_out, float* __restrict__ hn, float* __restrict__ cn,
    unsigned* __restrict__ flags0, unsigned* __restrict__ flags1, float* lds)
{
  const int j0 = bid_l * 8;
  const int bown = wid * 16 + l16;

  bf16x8 wx[2][8], wh[2][8];
  #pragma unroll
  for (int m = 0; m < 2; ++m){
    const int g = l16 & 3;
    const int u = 2 * (l16 >> 2) + m;
    const float* rx = Wih1 + (size_t)(g * HH + j0 + u) * HH;
    const float* rh = Whh1 + (size_t)(g * HH + j0 + u) * HH;
    #pragma unroll
    for (int kk = 0; kk < 8; ++kk){
      int k0 = wid * 256 + kk * 32 + kq;
      wx[m][kk] = pack8(*reinterpret_cast<const float4*>(rx + k0),
                        *reinterpret_cast<const float4*>(rx + k0 + 4));
      wh[m][kk] = pack8(*reinterpret_cast<const float4*>(rh + k0),
                        *reinterpret_cast<const float4*>(rh + k0 + 4));
    }
  }

  float cs[2];
  #pragma unroll
  for (int m = 0; m < 2; ++m)
    cs[m] = c0[(size_t)BBHH + (size_t)bown * HH + j0 + 2 * hi + m];
  float pooldec = 0.0f;
  const float dwv0 = decW[j0 + 2 * hi], dwv1 = decW[j0 + 2 * hi + 1];

  for (int t = 0; t < TT; ++t){
    f32x4 acc[2][4];
    #pragma unroll
    for (int m = 0; m < 2; ++m)
      #pragma unroll
      for (int nt = 0; nt < 4; ++nt)
        acc[m][nt] = (f32x4){0.f,0.f,0.f,0.f};

    // recurrent part first (own flag usually already satisfied) — overlaps L0's tail
    if (t > 0) wait_layer(flags1, (unsigned)t, lane);
    {
      const unsigned short* hs = (t == 0) ? h1i : hist1 + (size_t)(t - 1) * BBHH;
      const unsigned short* hr[4];
      #pragma unroll
      for (int nt = 0; nt < 4; ++nt)
        hr[nt] = hs + (size_t)(nt * 16 + l16) * HH;
      #pragma unroll
      for (int kk = 0; kk < 8; ++kk){
        const int kb = wid * 256 + kk * 32 + kq;
        #pragma unroll
        for (int nt = 0; nt < 4; ++nt){
          bf16x8 bf = *reinterpret_cast<const bf16x8*>(hr[nt] + kb);
          acc[0][nt] = __builtin_amdgcn_mfma_f32_16x16x32_bf16(wh[0][kk], bf, acc[0][nt], 0, 0, 0);
          acc[1][nt] = __builtin_amdgcn_mfma_f32_16x16x32_bf16(wh[1][kk], bf, acc[1][nt], 0, 0, 0);
        }
      }
    }

    // x-part: h0[t] from layer 0
    wait_layer(flags0, (unsigned)(t + 1), lane);
    {
      const unsigned short* xs = hist0 + (size_t)t * BBHH;
      const unsigned short* xr[4];
      #pragma unroll
      for (int nt = 0; nt < 4; ++nt)
        xr[nt] = xs + (size_t)(nt * 16 + l16) * HH;
      #pragma unroll
      for (int kk = 0; kk < 8; ++kk){
        const int kb = wid * 256 + kk * 32 + kq;
        #pragma unroll
        for (int nt = 0; nt < 4; ++nt){
          bf16x8 bf = *reinterpret_cast<const bf16x8*>(xr[nt] + kb);
          acc[0][nt] = __builtin_amdgcn_mfma_f32_16x16x32_bf16(wx[0][kk], bf, acc[0][nt], 0, 0, 0);
          acc[1][nt] = __builtin_amdgcn_mfma_f32_16x16x32_bf16(wx[1][kk], bf, acc[1][nt], 0, 0, 0);
        }
      }
    }

    #pragma unroll
    for (int m = 0; m < 2; ++m)
      #pragma unroll
      for (int nt = 0; nt < 4; ++nt)
        *reinterpret_cast<f32x4*>(&lds[LIDX(m, wid * 4 + nt)]) = acc[m][nt];
    __syncthreads();
    f32x4 s[2];
    #pragma unroll
    for (int m = 0; m < 2; ++m){
      s[m] = (f32x4){0.f,0.f,0.f,0.f};
      #pragma unroll
      for (int w = 0; w < 4; ++w)
        s[m] += *reinterpret_cast<f32x4*>(&lds[LIDX(m, w * 4 + wid)]);
    }

    float hv[2];
    #pragma unroll
    for (int m = 0; m < 2; ++m){
      float gi = sigmoidf_(s[m][0]), gf = sigmoidf_(s[m][1]);
      float gg = tanhf_(s[m][2]),    go = sigmoidf_(s[m][3]);
      cs[m] = gf * cs[m] + gi * gg;
      hv[m] = go * tanhf_(cs[m]);
    }
    unsigned w = (unsigned)f2b(hv[0]) | ((unsigned)f2b(hv[1]) << 16);
    __hip_atomic_store(reinterpret_cast<unsigned*>(hist1 + (size_t)t * BBHH + (size_t)bown * HH + j0 + 2 * hi),
                       w, __ATOMIC_RELAXED, __HIP_MEMORY_SCOPE_AGENT);
    pooldec += hv[0] * dwv0 + hv[1] * dwv1;
    if (t == TT - 1){
      size_t o = (size_t)BBHH + (size_t)bown * HH + j0 + 2 * hi;
      *reinterpret_cast<float2*>(hn + o) = make_float2(hv[0], hv[1]);
      *reinterpret_cast<float2*>(cn + o) = make_float2(cs[0], cs[1]);
    }

    publish(flags1, bid_l, (unsigned)(t + 1));
  }

  pooldec += __shfl_xor(pooldec, 16);
  pooldec += __shfl_xor(pooldec, 32);
  if (hi == 0){
    float contrib = pooldec * (1.0f / (float)TT);
    if (bid_l == 0) contrib += decb[0];
    atomicAdd(&dec_out[bown], contrib);
  }
}

__global__ __launch_bounds__(256, 1) void lstm_persist(
    const int* __restrict__ inputs, const float* __restrict__ c0,
    const unsigned short* __restrict__ emb_bf,
    const float* __restrict__ Wih0, const float* __restrict__ Whh0,
    const float* __restrict__ Wih1, const float* __restrict__ Whh1,
    const unsigned short* __restrict__ h0i, const unsigned short* __restrict__ h1i,
    unsigned short* __restrict__ hist0, unsigned short* __restrict__ hist1,
    const float* __restrict__ decW, const float* __restrict__ decb,
    float* __restrict__ dec_out, float* __restrict__ hn, float* __restrict__ cn,
    unsigned* __restrict__ flags)
{
  __shared__ float lds[2 * 16 * 64 * 4];   // 32 KB
  const int tid  = threadIdx.x;
  const int lane = tid & 63;
  const int wid  = tid >> 6;
  const int l16  = lane & 15;
  const int hi   = lane >> 4;
  const int kq   = hi << 3;
  unsigned* flags0 = flags;
  unsigned* flags1 = flags + 128;

  int bid = blockIdx.x;
  if (bid < BPL){
    run_l0(bid, lane, wid, l16, hi, kq, inputs, c0, emb_bf, Wih0, Whh0,
           h0i, hist0, hn, cn, flags0, lds);
  } else {
    run_l1(bid - BPL, lane, wid, l16, hi, kq, c0, Wih1, Whh1,
           h1i, hist0, hist1, decW, decb, dec_out, hn, cn, flags0, flags1, lds);
  }
}

extern "C" void kernel_launch(void* const* d_in, const int* in_sizes, int n_in,
                              void* d_out, int out_size, void* d_ws, size_t ws_size,
                              hipStream_t stream){
  const int*   inputs = (const int*)d_in[0];
  const float* h0     = (const float*)d_in[1];
  const float* c0     = (const float*)d_in[2];
  const float* emb    = (const float*)d_in[3];
  const float* Wih0   = (const float*)d_in[4];
  const float* Whh0   = (const float*)d_in[5];
  const float* Wih1   = (const float*)d_in[6];
  const float* Whh1   = (const float*)d_in[7];
  const float* decW   = (const float*)d_in[8];
  const float* decb   = (const float*)d_in[9];

  char* ws = (char*)d_ws;
  size_t off = 0;
  auto alloc = [&](size_t bytes) -> void* {
    void* p = ws + off;
    off += (bytes + 255) & ~(size_t)255;
    return p;
  };
  unsigned short* emb_bf = (unsigned short*)alloc((size_t)VV * EE * 2);      // 51.2 MB
  unsigned short* hist0  = (unsigned short*)alloc((size_t)TT * BBHH * 2);    // 64 MB
  unsigned short* hist1  = (unsigned short*)alloc((size_t)TT * BBHH * 2);    // 64 MB
  unsigned short* h0i    = (unsigned short*)alloc((size_t)BBHH * 2);
  unsigned short* h1i    = (unsigned short*)alloc((size_t)BBHH * 2);
  unsigned int*   flags  = (unsigned int*)alloc((size_t)256 * 4);

  float* out = (float*)d_out;            // decoded [B]
  float* hn  = out + BB;                 // [2,B,H]
  float* cn  = out + BB + 2 * BBHH;      // [2,B,H]

  hipMemsetAsync(flags, 0, 256 * 4, stream);
  hipMemsetAsync(out, 0, BB * 4, stream);

  cast_f2b<<<2048, 256, 0, stream>>>(emb, emb_bf, (long)VV * EE);
  init_h<<<BBHH / 256, 256, 0, stream>>>(h0, h0i, h1i);

  lstm_persist<<<NBLK, 256, 0, stream>>>(inputs, c0, emb_bf,
                                         Wih0, Whh0, Wih1, Whh1,
                                         h0i, h1i, hist0, hist1,
                                         decW, decb, out, hn, cn, flags);
}

// Round 6
// 4285.909 us; speedup vs baseline: 2.4508x; 1.8302x over previous
//
#include <hip/hip_runtime.h>

#define TT 512
#define BB 64
#define HH 1024
#define EE 512
#define VV 50000
#define BBHH (BB*HH)
#define BPL 128
#define NBLK 256

typedef __attribute__((ext_vector_type(8))) short bf16x8;
typedef __attribute__((ext_vector_type(4))) float f32x4;

__device__ inline unsigned short f2b(float f){
  unsigned int u; __builtin_memcpy(&u, &f, 4);
  unsigned int r = (u + 0x7FFFu + ((u >> 16) & 1u)) >> 16;
  return (unsigned short)r;
}
__device__ inline float sigmoidf_(float x){ return 1.0f / (1.0f + __expf(-x)); }
__device__ inline float tanhf_(float x){ float e = __expf(2.0f * x); return 1.0f - 2.0f / (e + 1.0f); }

__device__ inline bf16x8 pack8(float4 a, float4 b){
  bf16x8 r;
  r[0] = (short)f2b(a.x); r[1] = (short)f2b(a.y); r[2] = (short)f2b(a.z); r[3] = (short)f2b(a.w);
  r[4] = (short)f2b(b.x); r[5] = (short)f2b(b.y); r[6] = (short)f2b(b.z); r[7] = (short)f2b(b.w);
  return r;
}

// ---------------- cast fp32 -> bf16 ----------------
__global__ void cast_f2b(const float* __restrict__ src, unsigned short* __restrict__ dst, long n){
  long i = ((long)blockIdx.x * blockDim.x + threadIdx.x) * 4;
  long stride = (long)gridDim.x * blockDim.x * 4;
  for (; i + 3 < n; i += stride){
    float4 v = *reinterpret_cast<const float4*>(src + i);
    ushort4 r;
    r.x = f2b(v.x); r.y = f2b(v.y); r.z = f2b(v.z); r.w = f2b(v.w);
    *reinterpret_cast<ushort4*>(dst + i) = r;
  }
}

// ---------------- init: h0 fp32 [2,B,H] -> per-layer COMPACT bf16 init ----------------
// compact layout: [kblk=j>>3][b][u=j&7]
__global__ void init_h(const float* __restrict__ h0,
                       unsigned short* __restrict__ h0ic, unsigned short* __restrict__ h1ic){
  int i = blockIdx.x * blockDim.x + threadIdx.x;   // 0..BBHH-1, = b*HH + j
  int b = i >> 10, j = i & (HH - 1);
  int d = (((j >> 3) * BB) + b) * 8 + (j & 7);
  h0ic[d] = f2b(h0[i]);
  h1ic[d] = f2b(h0[BBHH + i]);
}

// ---------------- epoch-flag wait: all waves poll, WITH backoff ----------------
// flags[bid] = completed steps, plain relaxed agent store (no RMW).
__device__ __forceinline__ void wait_layer(const unsigned* __restrict__ f, unsigned e, int lane){
  unsigned a = __hip_atomic_load(f + lane,      __ATOMIC_RELAXED, __HIP_MEMORY_SCOPE_AGENT);
  unsigned b = __hip_atomic_load(f + 64 + lane, __ATOMIC_RELAXED, __HIP_MEMORY_SCOPE_AGENT);
  while (!__all(a >= e && b >= e)){
    __builtin_amdgcn_s_sleep(8);
    a = __hip_atomic_load(f + lane,      __ATOMIC_RELAXED, __HIP_MEMORY_SCOPE_AGENT);
    b = __hip_atomic_load(f + 64 + lane, __ATOMIC_RELAXED, __HIP_MEMORY_SCOPE_AGENT);
  }
}

// publish: drain this wave's sc1 stores, block-barrier, one flag store
__device__ __forceinline__ void publish(unsigned* __restrict__ f, int bid_l, unsigned e){
  asm volatile("s_waitcnt vmcnt(0)" ::: "memory");
  __syncthreads();
  if (threadIdx.x == 0)
    __hip_atomic_store(f + bid_l, e, __ATOMIC_RELAXED, __HIP_MEMORY_SCOPE_AGENT);
}

// Lane mapping (per m in 0..1): A-row l16 -> (g=l16&3, u=2*(l16>>2)+m);
// D row hi*4+i -> unit j0+2*hi+m, gate i; lane owns batch bown=wid*16+l16.
#define LIDX(m, s) ((((m) * 16 + (s)) * 64 + lane) * 4)

// consumer base offset into compact h: k = wid*256 + kk*32 + kq -> kblk = wid*32+kk*4+hi
// addr(units) = (kblk*BB + b)*8 ; b = nt*16+l16  =>  cbase + kk*2048 + nt*128
#define CBASE ((wid * 32 + hi) * (BB * 8) + l16 * 8)

__device__ void run_l0(
    int bid_l, int lane, int wid, int l16, int hi, int kq,
    const int* __restrict__ inputs, const float* __restrict__ c0,
    const unsigned short* __restrict__ emb_bf,
    const float* __restrict__ Wih0, const float* __restrict__ Whh0,
    const unsigned short* __restrict__ h0ic,
    unsigned short* __restrict__ hist0,
    float* __restrict__ hn, float* __restrict__ cn,
    unsigned* __restrict__ flags0, float* lds)
{
  const int j0 = bid_l * 8;
  const int bown = wid * 16 + l16;
  const int cbase = CBASE;

  bf16x8 wx[2][4], wh[2][8];
  #pragma unroll
  for (int m = 0; m < 2; ++m){
    const int g = l16 & 3;
    const int u = 2 * (l16 >> 2) + m;
    const float* rx = Wih0 + (size_t)(g * HH + j0 + u) * EE;
    const float* rh = Whh0 + (size_t)(g * HH + j0 + u) * HH;
    #pragma unroll
    for (int kk = 0; kk < 4; ++kk){
      int k0 = wid * 128 + kk * 32 + kq;
      wx[m][kk] = pack8(*reinterpret_cast<const float4*>(rx + k0),
                        *reinterpret_cast<const float4*>(rx + k0 + 4));
    }
    #pragma unroll
    for (int kk = 0; kk < 8; ++kk){
      int k0 = wid * 256 + kk * 32 + kq;
      wh[m][kk] = pack8(*reinterpret_cast<const float4*>(rh + k0),
                        *reinterpret_cast<const float4*>(rh + k0 + 4));
    }
  }

  float cs[2];
  #pragma unroll
  for (int m = 0; m < 2; ++m)
    cs[m] = c0[(size_t)bown * HH + j0 + 2 * hi + m];

  for (int t = 0; t < TT; ++t){
    f32x4 acc[2][4];
    #pragma unroll
    for (int m = 0; m < 2; ++m)
      #pragma unroll
      for (int nt = 0; nt < 4; ++nt)
        acc[m][nt] = (f32x4){0.f,0.f,0.f,0.f};

    // x-part (emb) before the wait — dependency-free
    {
      const unsigned short* xr[4];
      #pragma unroll
      for (int nt = 0; nt < 4; ++nt)
        xr[nt] = emb_bf + (size_t)inputs[t * BB + nt * 16 + l16] * EE;
      #pragma unroll
      for (int kk = 0; kk < 4; ++kk){
        const int kb = wid * 128 + kk * 32 + kq;
        #pragma unroll
        for (int nt = 0; nt < 4; ++nt){
          bf16x8 bf = *reinterpret_cast<const bf16x8*>(xr[nt] + kb);
          acc[0][nt] = __builtin_amdgcn_mfma_f32_16x16x32_bf16(wx[0][kk], bf, acc[0][nt], 0, 0, 0);
          acc[1][nt] = __builtin_amdgcn_mfma_f32_16x16x32_bf16(wx[1][kk], bf, acc[1][nt], 0, 0, 0);
        }
      }
    }

    if (t > 0) wait_layer(flags0, (unsigned)t, lane);

    // recurrent part (compact layout, full-line coalesced)
    {
      const unsigned short* hs = (t == 0) ? h0ic : hist0 + (size_t)(t - 1) * BBHH;
      #pragma unroll
      for (int kk = 0; kk < 8; ++kk){
        #pragma unroll
        for (int nt = 0; nt < 4; ++nt){
          bf16x8 bf = *reinterpret_cast<const bf16x8*>(hs + cbase + kk * 2048 + nt * 128);
          acc[0][nt] = __builtin_amdgcn_mfma_f32_16x16x32_bf16(wh[0][kk], bf, acc[0][nt], 0, 0, 0);
          acc[1][nt] = __builtin_amdgcn_mfma_f32_16x16x32_bf16(wh[1][kk], bf, acc[1][nt], 0, 0, 0);
        }
      }
    }

    // cross-wave K reduction (dense 16B/lane -> 0 bank conflicts)
    #pragma unroll
    for (int m = 0; m < 2; ++m)
      #pragma unroll
      for (int nt = 0; nt < 4; ++nt)
        *reinterpret_cast<f32x4*>(&lds[LIDX(m, wid * 4 + nt)]) = acc[m][nt];
    __syncthreads();
    f32x4 s[2];
    #pragma unroll
    for (int m = 0; m < 2; ++m){
      s[m] = (f32x4){0.f,0.f,0.f,0.f};
      #pragma unroll
      for (int w = 0; w < 4; ++w)
        s[m] += *reinterpret_cast<f32x4*>(&lds[LIDX(m, w * 4 + wid)]);
    }

    float hv[2];
    #pragma unroll
    for (int m = 0; m < 2; ++m){
      float gi = sigmoidf_(s[m][0]), gf = sigmoidf_(s[m][1]);
      float gg = tanhf_(s[m][2]),    go = sigmoidf_(s[m][3]);
      cs[m] = gf * cs[m] + gi * gg;
      hv[m] = go * tanhf_(cs[m]);
    }
    // publish: compact layout, block region = 1KB contiguous (8 full lines)
    unsigned w = (unsigned)f2b(hv[0]) | ((unsigned)f2b(hv[1]) << 16);
    __hip_atomic_store(reinterpret_cast<unsigned*>(hist0 + (size_t)t * BBHH + (size_t)(bid_l * BB + bown) * 8 + 2 * hi),
                       w, __ATOMIC_RELAXED, __HIP_MEMORY_SCOPE_AGENT);
    if (t == TT - 1){
      size_t o = (size_t)bown * HH + j0 + 2 * hi;
      *reinterpret_cast<float2*>(hn + o) = make_float2(hv[0], hv[1]);
      *reinterpret_cast<float2*>(cn + o) = make_float2(cs[0], cs[1]);
    }

    publish(flags0, bid_l, (unsigned)(t + 1));
  }
}

__device__ void run_l1(
    int bid_l, int lane, int wid, int l16, int hi, int kq,
    const float* __restrict__ c0,
    const float* __restrict__ Wih1, const float* __restrict__ Whh1,
    const unsigned short* __restrict__ h1ic,
    const unsigned short* __restrict__ hist0, unsigned short* __restrict__ hist1,
    const float* __restrict__ decW, const float* __restrict__ decb,
    float* __restrict__ dec_out, float* __restrict__ hn, float* __restrict__ cn,
    unsigned* __restrict__ flags0, unsigned* __restrict__ flags1, float* lds)
{
  const int j0 = bid_l * 8;
  const int bown = wid * 16 + l16;
  const int cbase = CBASE;

  bf16x8 wx[2][8], wh[2][8];
  #pragma unroll
  for (int m = 0; m < 2; ++m){
    const int g = l16 & 3;
    const int u = 2 * (l16 >> 2) + m;
    const float* rx = Wih1 + (size_t)(g * HH + j0 + u) * HH;
    const float* rh = Whh1 + (size_t)(g * HH + j0 + u) * HH;
    #pragma unroll
    for (int kk = 0; kk < 8; ++kk){
      int k0 = wid * 256 + kk * 32 + kq;
      wx[m][kk] = pack8(*reinterpret_cast<const float4*>(rx + k0),
                        *reinterpret_cast<const float4*>(rx + k0 + 4));
      wh[m][kk] = pack8(*reinterpret_cast<const float4*>(rh + k0),
                        *reinterpret_cast<const float4*>(rh + k0 + 4));
    }
  }

  float cs[2];
  #pragma unroll
  for (int m = 0; m < 2; ++m)
    cs[m] = c0[(size_t)BBHH + (size_t)bown * HH + j0 + 2 * hi + m];
  float pooldec = 0.0f;
  const float dwv0 = decW[j0 + 2 * hi], dwv1 = decW[j0 + 2 * hi + 1];

  for (int t = 0; t < TT; ++t){
    f32x4 acc[2][4];
    #pragma unroll
    for (int m = 0; m < 2; ++m)
      #pragma unroll
      for (int nt = 0; nt < 4; ++nt)
        acc[m][nt] = (f32x4){0.f,0.f,0.f,0.f};

    // recurrent part first (own flag usually already satisfied) — overlaps L0's tail
    if (t > 0) wait_layer(flags1, (unsigned)t, lane);
    {
      const unsigned short* hs = (t == 0) ? h1ic : hist1 + (size_t)(t - 1) * BBHH;
      #pragma unroll
      for (int kk = 0; kk < 8; ++kk){
        #pragma unroll
        for (int nt = 0; nt < 4; ++nt){
          bf16x8 bf = *reinterpret_cast<const bf16x8*>(hs + cbase + kk * 2048 + nt * 128);
          acc[0][nt] = __builtin_amdgcn_mfma_f32_16x16x32_bf16(wh[0][kk], bf, acc[0][nt], 0, 0, 0);
          acc[1][nt] = __builtin_amdgcn_mfma_f32_16x16x32_bf16(wh[1][kk], bf, acc[1][nt], 0, 0, 0);
        }
      }
    }

    // x-part: h0[t] from layer 0
    wait_layer(flags0, (unsigned)(t + 1), lane);
    {
      const unsigned short* xs = hist0 + (size_t)t * BBHH;
      #pragma unroll
      for (int kk = 0; kk < 8; ++kk){
        #pragma unroll
        for (int nt = 0; nt < 4; ++nt){
          bf16x8 bf = *reinterpret_cast<const bf16x8*>(xs + cbase + kk * 2048 + nt * 128);
          acc[0][nt] = __builtin_amdgcn_mfma_f32_16x16x32_bf16(wx[0][kk], bf, acc[0][nt], 0, 0, 0);
          acc[1][nt] = __builtin_amdgcn_mfma_f32_16x16x32_bf16(wx[1][kk], bf, acc[1][nt], 0, 0, 0);
        }
      }
    }

    #pragma unroll
    for (int m = 0; m < 2; ++m)
      #pragma unroll
      for (int nt = 0; nt < 4; ++nt)
        *reinterpret_cast<f32x4*>(&lds[LIDX(m, wid * 4 + nt)]) = acc[m][nt];
    __syncthreads();
    f32x4 s[2];
    #pragma unroll
    for (int m = 0; m < 2; ++m){
      s[m] = (f32x4){0.f,0.f,0.f,0.f};
      #pragma unroll
      for (int w = 0; w < 4; ++w)
        s[m] += *reinterpret_cast<f32x4*>(&lds[LIDX(m, w * 4 + wid)]);
    }

    float hv[2];
    #pragma unroll
    for (int m = 0; m < 2; ++m){
      float gi = sigmoidf_(s[m][0]), gf = sigmoidf_(s[m][1]);
      float gg = tanhf_(s[m][2]),    go = sigmoidf_(s[m][3]);
      cs[m] = gf * cs[m] + gi * gg;
      hv[m] = go * tanhf_(cs[m]);
    }
    unsigned w = (unsigned)f2b(hv[0]) | ((unsigned)f2b(hv[1]) << 16);
    __hip_atomic_store(reinterpret_cast<unsigned*>(hist1 + (size_t)t * BBHH + (size_t)(bid_l * BB + bown) * 8 + 2 * hi),
                       w, __ATOMIC_RELAXED, __HIP_MEMORY_SCOPE_AGENT);
    pooldec += hv[0] * dwv0 + hv[1] * dwv1;
    if (t == TT - 1){
      size_t o = (size_t)BBHH + (size_t)bown * HH + j0 + 2 * hi;
      *reinterpret_cast<float2*>(hn + o) = make_float2(hv[0], hv[1]);
      *reinterpret_cast<float2*>(cn + o) = make_float2(cs[0], cs[1]);
    }

    publish(flags1, bid_l, (unsigned)(t + 1));
  }

  pooldec += __shfl_xor(pooldec, 16);
  pooldec += __shfl_xor(pooldec, 32);
  if (hi == 0){
    float contrib = pooldec * (1.0f / (float)TT);
    if (bid_l == 0) contrib += decb[0];
    atomicAdd(&dec_out[bown], contrib);
  }
}

__global__ __launch_bounds__(256, 1) void lstm_persist(
    const int* __restrict__ inputs, const float* __restrict__ c0,
    const unsigned short* __restrict__ emb_bf,
    const float* __restrict__ Wih0, const float* __restrict__ Whh0,
    const float* __restrict__ Wih1, const float* __restrict__ Whh1,
    const unsigned short* __restrict__ h0ic, const unsigned short* __restrict__ h1ic,
    unsigned short* __restrict__ hist0, unsigned short* __restrict__ hist1,
    const float* __restrict__ decW, const float* __restrict__ decb,
    float* __restrict__ dec_out, float* __restrict__ hn, float* __restrict__ cn,
    unsigned* __restrict__ flags)
{
  __shared__ float lds[2 * 16 * 64 * 4];   // 32 KB
  const int tid  = threadIdx.x;
  const int lane = tid & 63;
  const int wid  = tid >> 6;
  const int l16  = lane & 15;
  const int hi   = lane >> 4;
  const int kq   = hi << 3;
  unsigned* flags0 = flags;
  unsigned* flags1 = flags + 128;

  int bid = blockIdx.x;
  if (bid < BPL){
    run_l0(bid, lane, wid, l16, hi, kq, inputs, c0, emb_bf, Wih0, Whh0,
           h0ic, hist0, hn, cn, flags0, lds);
  } else {
    run_l1(bid - BPL, lane, wid, l16, hi, kq, c0, Wih1, Whh1,
           h1ic, hist0, hist1, decW, decb, dec_out, hn, cn, flags0, flags1, lds);
  }
}

extern "C" void kernel_launch(void* const* d_in, const int* in_sizes, int n_in,
                              void* d_out, int out_size, void* d_ws, size_t ws_size,
                              hipStream_t stream){
  const int*   inputs = (const int*)d_in[0];
  const float* h0     = (const float*)d_in[1];
  const float* c0     = (const float*)d_in[2];
  const float* emb    = (const float*)d_in[3];
  const float* Wih0   = (const float*)d_in[4];
  const float* Whh0   = (const float*)d_in[5];
  const float* Wih1   = (const float*)d_in[6];
  const float* Whh1   = (const float*)d_in[7];
  const float* decW   = (const float*)d_in[8];
  const float* decb   = (const float*)d_in[9];

  char* ws = (char*)d_ws;
  size_t off = 0;
  auto alloc = [&](size_t bytes) -> void* {
    void* p = ws + off;
    off += (bytes + 255) & ~(size_t)255;
    return p;
  };
  unsigned short* emb_bf = (unsigned short*)alloc((size_t)VV * EE * 2);      // 51.2 MB
  unsigned short* hist0  = (unsigned short*)alloc((size_t)TT * BBHH * 2);    // 64 MB
  unsigned short* hist1  = (unsigned short*)alloc((size_t)TT * BBHH * 2);    // 64 MB
  unsigned short* h0ic   = (unsigned short*)alloc((size_t)BBHH * 2);
  unsigned short* h1ic   = (unsigned short*)alloc((size_t)BBHH * 2);
  unsigned int*   flags  = (unsigned int*)alloc((size_t)256 * 4);

  float* out = (float*)d_out;            // decoded [B]
  float* hn  = out + BB;                 // [2,B,H]
  float* cn  = out + BB + 2 * BBHH;      // [2,B,H]

  hipMemsetAsync(flags, 0, 256 * 4, stream);
  hipMemsetAsync(out, 0, BB * 4, stream);

  cast_f2b<<<2048, 256, 0, stream>>>(emb, emb_bf, (long)VV * EE);
  init_h<<<BBHH / 256, 256, 0, stream>>>(h0, h0ic, h1ic);

  lstm_persist<<<NBLK, 256, 0, stream>>>(inputs, c0, emb_bf,
                                         Wih0, Whh0, Wih1, Whh1,
                                         h0ic, h1ic, hist0, hist1,
                                         decW, decb, out, hn, cn, flags);
}